// Round 3
// baseline (383.326 us; speedup 1.0000x reference)
//
#include <hip/hip_runtime.h>

#define D 128
#define EPS 1e-5f

typedef __attribute__((ext_vector_type(8))) short bf16x8;
typedef __attribute__((ext_vector_type(4))) float floatx4;

// fp32 -> bf16 round-to-nearest-even (bit trick; NaN irrelevant here)
__device__ __forceinline__ unsigned short f2bf(float f) {
    union { float f; unsigned u; } v; v.f = f;
    unsigned r = v.u + 0x7fffu + ((v.u >> 16) & 1u);
    return (unsigned short)(r >> 16);
}
__device__ __forceinline__ float bf2f(unsigned short s) {
    union { unsigned u; float f; } v; v.u = ((unsigned)s) << 16; return v.f;
}

// ---------------- prep: transpose+convert 3 weight matrices to bf16 Wt[f][k]; zero counts ----
__global__ __launch_bounds__(256) void prep(const float* __restrict__ W0,
                                            const float* __restrict__ W1,
                                            const float* __restrict__ W2,
                                            unsigned short* __restrict__ wt,
                                            int* __restrict__ counts, int nN) {
    int idx = blockIdx.x * 256 + threadIdx.x;
    if (idx < 3 * D * D) {
        int w = idx >> 14;           // D*D = 16384
        int r = idx & (D * D - 1);
        int f = r >> 7, k = r & (D - 1);
        const float* W = (w == 0) ? W0 : (w == 1) ? W1 : W2;
        wt[(size_t)w * D * D + (size_t)f * D + k] = f2bf(W[(size_t)k * D + f]);
    }
    if (idx < nN) counts[idx] = 0;
}

// ---------------- CSR build ----------------
__global__ __launch_bounds__(256) void hist_dst(const int* __restrict__ dst,
                                                int* __restrict__ counts, int nE) {
    int e = blockIdx.x * 256 + threadIdx.x;
    if (e < nE) atomicAdd(&counts[dst[e]], 1);
}

// single-block exclusive scan of counts -> offsets, cursor (nN up to 1024*CH)
__global__ __launch_bounds__(1024) void scan_block(const int* __restrict__ counts,
                                                   int* __restrict__ offsets,
                                                   int* __restrict__ cursor, int nN, int nE) {
    __shared__ int sh[1024];
    const int t = threadIdx.x;
    const int CH = (nN + 1023) / 1024;
    const int base = t * CH;
    int s = 0;
    for (int i = 0; i < CH; ++i) {
        int idx = base + i;
        if (idx < nN) s += counts[idx];
    }
    sh[t] = s;
    __syncthreads();
    int val = s;
    for (int off = 1; off < 1024; off <<= 1) {
        int u = (t >= off) ? sh[t - off] : 0;
        __syncthreads();
        val += u;
        sh[t] = val;
        __syncthreads();
    }
    int run = val - s;   // exclusive prefix
    for (int i = 0; i < CH; ++i) {
        int idx = base + i;
        if (idx < nN) {
            offsets[idx] = run;
            cursor[idx] = run;
            run += counts[idx];
        }
    }
    if (t == 0) offsets[nN] = nE;
}

__global__ __launch_bounds__(256) void fill_edges(const int* __restrict__ src,
                                                  const int* __restrict__ dst,
                                                  int* __restrict__ cursor,
                                                  int* __restrict__ edge_src, int nE) {
    int e = blockIdx.x * 256 + threadIdx.x;
    if (e < nE) {
        int pos = atomicAdd(&cursor[dst[e]], 1);
        edge_src[pos] = src[e];
    }
}

// ---------------- gather segment-sum over bf16 rows, fp32 accumulate ----------------
// 32 lanes per node, ushort4 (4 bf16, 8B) per lane; 8 nodes per 256-thread block.
__global__ __launch_bounds__(256) void gather_sum(const unsigned short* __restrict__ hpre,
                                                  const int* __restrict__ offsets,
                                                  const int* __restrict__ edge_src,
                                                  unsigned short* __restrict__ agg, int nN) {
    const int t = threadIdx.x;
    const int lane = t & 31;
    const int n = blockIdx.x * 8 + (t >> 5);
    if (n >= nN) return;
    const int beg = offsets[n], end = offsets[n + 1];
    const ushort4* H = (const ushort4*)hpre;
    float ax = 0.f, ay = 0.f, az = 0.f, aw = 0.f;
    for (int j = beg; j < end; ++j) {
        int s = edge_src[j];
        ushort4 v = H[(size_t)s * 32 + lane];
        ax += bf2f(v.x); ay += bf2f(v.y); az += bf2f(v.z); aw += bf2f(v.w);
    }
    ushort4 o;
    o.x = f2bf(ax); o.y = f2bf(ay); o.z = f2bf(az); o.w = f2bf(aw);
    ((ushort4*)agg)[(size_t)n * 32 + lane] = o;
}

// ---------------- MFMA GEMM: Y = act(X @ W + b), X rows = B-operand, Wt rows = A-operand ----
// Wave handles 16 node rows. A=Wt -> D[feature][node]; C-layout: node=lane&15 (fixed per lane),
// features = tile*16 + quad*4 + {0..3}  -> contiguous per-lane stores.
template <bool FP32IN, bool RELU>
__global__ __launch_bounds__(256) void gemm_mfma(const void* __restrict__ Xv,
                                                 const unsigned short* __restrict__ Wt,
                                                 const float* __restrict__ bias,
                                                 unsigned short* __restrict__ Y, int nrows) {
    const int t = threadIdx.x;
    const int lane = t & 63, wave = t >> 6;
    const int ml = lane & 15, q = lane >> 4;
    const int node = blockIdx.x * 64 + wave * 16 + ml;
    const int rr = (node < nrows) ? node : (nrows - 1);
    const bool ok = (node < nrows);

    bf16x8 bfrag[4];
    if (FP32IN) {
        const float* xp = (const float*)Xv + (size_t)rr * D + q * 8;
#pragma unroll
        for (int kb = 0; kb < 4; ++kb) {
            float4 f0 = *(const float4*)(xp + kb * 32);
            float4 f1 = *(const float4*)(xp + kb * 32 + 4);
            bf16x8 v;
            v[0] = (short)f2bf(f0.x); v[1] = (short)f2bf(f0.y);
            v[2] = (short)f2bf(f0.z); v[3] = (short)f2bf(f0.w);
            v[4] = (short)f2bf(f1.x); v[5] = (short)f2bf(f1.y);
            v[6] = (short)f2bf(f1.z); v[7] = (short)f2bf(f1.w);
            bfrag[kb] = v;
        }
    } else {
        const unsigned short* xp = (const unsigned short*)Xv + (size_t)rr * D + q * 8;
#pragma unroll
        for (int kb = 0; kb < 4; ++kb) bfrag[kb] = *(const bf16x8*)(xp + kb * 32);
    }

#pragma unroll
    for (int tl = 0; tl < 8; ++tl) {
        floatx4 acc = {0.f, 0.f, 0.f, 0.f};
        const unsigned short* wp = Wt + (size_t)(tl * 16 + ml) * D + q * 8;
#pragma unroll
        for (int kb = 0; kb < 4; ++kb) {
            bf16x8 af = *(const bf16x8*)(wp + kb * 32);
            acc = __builtin_amdgcn_mfma_f32_16x16x32_bf16(af, bfrag[kb], acc, 0, 0, 0);
        }
        const int f0i = tl * 16 + q * 4;
        float4 b4 = *(const float4*)(bias + f0i);
        if (ok) {
            float o0 = acc[0] + b4.x, o1 = acc[1] + b4.y;
            float o2 = acc[2] + b4.z, o3 = acc[3] + b4.w;
            if (RELU) {
                o0 = fmaxf(o0, 0.f); o1 = fmaxf(o1, 0.f);
                o2 = fmaxf(o2, 0.f); o3 = fmaxf(o3, 0.f);
            }
            ushort4 o;
            o.x = f2bf(o0); o.y = f2bf(o1); o.z = f2bf(o2); o.w = f2bf(o3);
            *(ushort4*)(Y + (size_t)node * D + f0i) = o;
        }
    }
}

// ---------------- final MFMA GEMM fused with bias+relu+residual+LayerNorm ----------------
__global__ __launch_bounds__(256) void gemm_ln(const unsigned short* __restrict__ X,
                                               const unsigned short* __restrict__ Wt,
                                               const float* __restrict__ bias,
                                               const unsigned short* __restrict__ Hres,
                                               const float* __restrict__ gamma,
                                               const float* __restrict__ beta,
                                               float* __restrict__ out, int nrows) {
    const int t = threadIdx.x;
    const int lane = t & 63, wave = t >> 6;
    const int ml = lane & 15, q = lane >> 4;
    const int node = blockIdx.x * 64 + wave * 16 + ml;
    const int rr = (node < nrows) ? node : (nrows - 1);
    const bool ok = (node < nrows);

    bf16x8 bfrag[4];
    const unsigned short* xp = X + (size_t)rr * D + q * 8;
#pragma unroll
    for (int kb = 0; kb < 4; ++kb) bfrag[kb] = *(const bf16x8*)(xp + kb * 32);

    float vs[8][4];
    float sm = 0.f, sq = 0.f;
#pragma unroll
    for (int tl = 0; tl < 8; ++tl) {
        floatx4 acc = {0.f, 0.f, 0.f, 0.f};
        const unsigned short* wp = Wt + (size_t)(tl * 16 + ml) * D + q * 8;
#pragma unroll
        for (int kb = 0; kb < 4; ++kb) {
            bf16x8 af = *(const bf16x8*)(wp + kb * 32);
            acc = __builtin_amdgcn_mfma_f32_16x16x32_bf16(af, bfrag[kb], acc, 0, 0, 0);
        }
        const int f0i = tl * 16 + q * 4;
        float4 b4 = *(const float4*)(bias + f0i);
        ushort4 hr = ((const ushort4*)(Hres + (size_t)rr * D + f0i))[0];
        float a0 = fmaxf(acc[0] + b4.x, 0.f) + bf2f(hr.x);
        float a1 = fmaxf(acc[1] + b4.y, 0.f) + bf2f(hr.y);
        float a2 = fmaxf(acc[2] + b4.z, 0.f) + bf2f(hr.z);
        float a3 = fmaxf(acc[3] + b4.w, 0.f) + bf2f(hr.w);
        vs[tl][0] = a0; vs[tl][1] = a1; vs[tl][2] = a2; vs[tl][3] = a3;
        sm += a0 + a1 + a2 + a3;
        sq += a0 * a0 + a1 * a1 + a2 * a2 + a3 * a3;
    }

    // full 128-feature row of node (lane&15) is spread across the 4 quads -> xor 16, 32
    sm += __shfl_xor(sm, 16); sm += __shfl_xor(sm, 32);
    sq += __shfl_xor(sq, 16); sq += __shfl_xor(sq, 32);

    const float mu = sm * (1.f / D);
    const float var = sq * (1.f / D) - mu * mu;
    const float is = rsqrtf(var + EPS);

    if (ok) {
#pragma unroll
        for (int tl = 0; tl < 8; ++tl) {
            const int f0i = tl * 16 + q * 4;
            float4 g4 = *(const float4*)(gamma + f0i);
            float4 be4 = *(const float4*)(beta + f0i);
            float4 o;
            o.x = (vs[tl][0] - mu) * is * g4.x + be4.x;
            o.y = (vs[tl][1] - mu) * is * g4.y + be4.y;
            o.z = (vs[tl][2] - mu) * is * g4.z + be4.z;
            o.w = (vs[tl][3] - mu) * is * g4.w + be4.w;
            *(float4*)(out + (size_t)node * D + f0i) = o;
        }
    }
}

extern "C" void kernel_launch(void* const* d_in, const int* in_sizes, int n_in,
                              void* d_out, int out_size, void* d_ws, size_t ws_size,
                              hipStream_t stream) {
    const float* h     = (const float*)d_in[0];
    const int*   src   = (const int*)d_in[1];
    const int*   dst   = (const int*)d_in[2];
    const float* W_pre = (const float*)d_in[3];
    const float* b_pre = (const float*)d_in[4];
    const float* W1    = (const float*)d_in[5];
    const float* b1    = (const float*)d_in[6];
    const float* W2    = (const float*)d_in[7];
    const float* b2    = (const float*)d_in[8];
    const float* gamma = (const float*)d_in[9];
    const float* beta  = (const float*)d_in[10];
    float* out = (float*)d_out;

    const int nN = in_sizes[0] / D;   // 50000
    const int nE = in_sizes[1];       // 600000
    const size_t rowsz = (size_t)nN * D;   // elements per node matrix

    // ---- workspace layout (bf16 stage buffers, then ints) ----
    unsigned short* hpre = (unsigned short*)d_ws;      // [nN*D] bf16
    unsigned short* agg  = hpre + rowsz;               // [nN*D] bf16
    unsigned short* t1   = agg + rowsz;                // [nN*D] bf16
    unsigned short* wt   = t1 + rowsz;                 // [3*D*D] bf16 (Wt = W^T)
    int* edge_src  = (int*)(wt + 3 * D * D);           // [nE]
    int* offsets   = edge_src + nE;                    // [nN+1]
    int* cursor    = offsets + nN + 1;                 // [nN]
    int* counts    = cursor + nN;                      // [nN]

    const int prep_n   = (3 * D * D > nN) ? 3 * D * D : nN;
    const int eblocks  = (nE + 255) / 256;
    const int gblocks  = (nN + 63) / 64;    // 64 node rows per block (4 waves x 16)
    const int gatherbl = (nN + 7) / 8;

    // CSR build + weight prep
    prep<<<(prep_n + 255) / 256, 256, 0, stream>>>(W_pre, W1, W2, wt, counts, nN);
    hist_dst<<<eblocks, 256, 0, stream>>>(dst, counts, nE);
    scan_block<<<1, 1024, 0, stream>>>(counts, offsets, cursor, nN, nE);
    fill_edges<<<eblocks, 256, 0, stream>>>(src, dst, cursor, edge_src, nE);

    // compute
    gemm_mfma<true, false><<<gblocks, 256, 0, stream>>>(h, wt, b_pre, hpre, nN);
    gather_sum<<<gatherbl, 256, 0, stream>>>(hpre, offsets, edge_src, agg, nN);
    gemm_mfma<false, true><<<gblocks, 256, 0, stream>>>(agg, wt + D * D, b1, t1, nN);
    gemm_ln<<<gblocks, 256, 0, stream>>>(t1, wt + 2 * D * D, b2, hpre, gamma, beta, out, nN);
}

// Round 4
// 299.582 us; speedup vs baseline: 1.2795x; 1.2795x over previous
//
#include <hip/hip_runtime.h>

#define D 128
#define EPS 1e-5f
#define SCAN_CHUNK 1024   // elements per scan block (256 thr x 4)
#define TSTRIDE 136       // LDS tile row stride in shorts (272 B = 17*16 -> 16B aligned, 2-way banks)

typedef __attribute__((ext_vector_type(8))) short bf16x8;
typedef __attribute__((ext_vector_type(4))) float floatx4;

// fp32 -> bf16 round-to-nearest-even
__device__ __forceinline__ unsigned short f2bf(float f) {
    union { float f; unsigned u; } v; v.f = f;
    unsigned r = v.u + 0x7fffu + ((v.u >> 16) & 1u);
    return (unsigned short)(r >> 16);
}
__device__ __forceinline__ float bf2f(unsigned short s) {
    union { unsigned u; float f; } v; v.u = ((unsigned)s) << 16; return v.f;
}

// ---------------- prep: transpose+convert 3 weight matrices to bf16 Wt[f][k]; zero counts ----
__global__ __launch_bounds__(256) void prep(const float* __restrict__ W0,
                                            const float* __restrict__ W1,
                                            const float* __restrict__ W2,
                                            unsigned short* __restrict__ wt,
                                            int* __restrict__ counts, int nN) {
    int idx = blockIdx.x * 256 + threadIdx.x;
    if (idx < 3 * D * D) {
        int w = idx >> 14;
        int r = idx & (D * D - 1);
        int f = r >> 7, k = r & (D - 1);
        const float* W = (w == 0) ? W0 : (w == 1) ? W1 : W2;
        wt[(size_t)w * D * D + (size_t)f * D + k] = f2bf(W[(size_t)k * D + f]);
    }
    if (idx < nN) counts[idx] = 0;
}

// ---------------- CSR build ----------------
__global__ __launch_bounds__(256) void hist_dst(const int* __restrict__ dst,
                                                int* __restrict__ counts, int nE) {
    int e = blockIdx.x * 256 + threadIdx.x;
    if (e < nE) atomicAdd(&counts[dst[e]], 1);
}

__global__ __launch_bounds__(256) void scan_chunk_sums(const int* __restrict__ counts,
                                                       int* __restrict__ chunkSums, int n) {
    __shared__ int sh[256];
    const int t = threadIdx.x;
    const int base = blockIdx.x * SCAN_CHUNK + t * 4;
    int s = 0;
#pragma unroll
    for (int i = 0; i < 4; ++i) {
        int idx = base + i;
        if (idx < n) s += counts[idx];
    }
    sh[t] = s;
    __syncthreads();
    for (int off = 128; off > 0; off >>= 1) {
        if (t < off) sh[t] += sh[t + off];
        __syncthreads();
    }
    if (t == 0) chunkSums[blockIdx.x] = sh[0];
}

__global__ __launch_bounds__(64) void scan_top(int* __restrict__ chunkSums, int nChunks,
                                               int* __restrict__ offsets, int nN, int nE) {
    const int t = threadIdx.x;
    int orig = (t < nChunks) ? chunkSums[t] : 0;
    int v = orig;
#pragma unroll
    for (int off = 1; off < 64; off <<= 1) {
        int u = __shfl_up(v, off, 64);
        if (t >= off) v += u;
    }
    if (t < nChunks) chunkSums[t] = v - orig;   // exclusive
    if (t == 0) offsets[nN] = nE;
}

__global__ __launch_bounds__(256) void scan_final(const int* __restrict__ counts,
                                                  const int* __restrict__ chunkSums,
                                                  int* __restrict__ offsets,
                                                  int* __restrict__ cursor, int n) {
    __shared__ int sh[256];
    const int t = threadIdx.x;
    const int base = blockIdx.x * SCAN_CHUNK + t * 4;
    int c[4];
    int s = 0;
#pragma unroll
    for (int i = 0; i < 4; ++i) {
        int idx = base + i;
        c[i] = (idx < n) ? counts[idx] : 0;
        s += c[i];
    }
    sh[t] = s;
    __syncthreads();
    int val = s;
    for (int off = 1; off < 256; off <<= 1) {
        int u = (t >= off) ? sh[t - off] : 0;
        __syncthreads();
        val += u;
        sh[t] = val;
        __syncthreads();
    }
    int run = val - s + chunkSums[blockIdx.x];
#pragma unroll
    for (int i = 0; i < 4; ++i) {
        int idx = base + i;
        if (idx < n) {
            offsets[idx] = run;
            cursor[idx] = run;
        }
        run += c[i];
    }
}

__global__ __launch_bounds__(256) void fill_edges(const int* __restrict__ src,
                                                  const int* __restrict__ dst,
                                                  int* __restrict__ cursor,
                                                  int* __restrict__ edge_src, int nE) {
    int e = blockIdx.x * 256 + threadIdx.x;
    if (e < nE) {
        int pos = atomicAdd(&cursor[dst[e]], 1);
        edge_src[pos] = src[e];
    }
}

// ---------------- GEMM1: hpre = h @ W_pre + b_pre (fp32 in, bf16 out) ----------------
__global__ __launch_bounds__(256) void gemm1(const float* __restrict__ X,
                                             const unsigned short* __restrict__ Wt,
                                             const float* __restrict__ bias,
                                             unsigned short* __restrict__ Y, int nrows) {
    const int t = threadIdx.x;
    const int lane = t & 63, wave = t >> 6;
    const int ml = lane & 15, q = lane >> 4;
    const int node = blockIdx.x * 64 + wave * 16 + ml;
    const int rr = (node < nrows) ? node : (nrows - 1);
    const bool ok = (node < nrows);

    bf16x8 bfrag[4];
    const float* xp = X + (size_t)rr * D + q * 8;
#pragma unroll
    for (int kb = 0; kb < 4; ++kb) {
        float4 f0 = *(const float4*)(xp + kb * 32);
        float4 f1 = *(const float4*)(xp + kb * 32 + 4);
        bf16x8 v;
        v[0] = (short)f2bf(f0.x); v[1] = (short)f2bf(f0.y);
        v[2] = (short)f2bf(f0.z); v[3] = (short)f2bf(f0.w);
        v[4] = (short)f2bf(f1.x); v[5] = (short)f2bf(f1.y);
        v[6] = (short)f2bf(f1.z); v[7] = (short)f2bf(f1.w);
        bfrag[kb] = v;
    }

#pragma unroll
    for (int tl = 0; tl < 8; ++tl) {
        floatx4 acc = {0.f, 0.f, 0.f, 0.f};
        const unsigned short* wp = Wt + (size_t)(tl * 16 + ml) * D + q * 8;
#pragma unroll
        for (int kb = 0; kb < 4; ++kb) {
            bf16x8 af = *(const bf16x8*)(wp + kb * 32);
            acc = __builtin_amdgcn_mfma_f32_16x16x32_bf16(af, bfrag[kb], acc, 0, 0, 0);
        }
        const int f0i = tl * 16 + q * 4;
        float4 b4 = *(const float4*)(bias + f0i);
        if (ok) {
            ushort4 o;
            o.x = f2bf(acc[0] + b4.x); o.y = f2bf(acc[1] + b4.y);
            o.z = f2bf(acc[2] + b4.z); o.w = f2bf(acc[3] + b4.w);
            *(ushort4*)(Y + (size_t)node * D + f0i) = o;
        }
    }
}

// ---------------- fused tail: gather -> GEMM2(relu) -> GEMM3 -> +res -> LayerNorm ----------------
// Block = 256 threads = 4 waves = 64 nodes (16 per wave). LDS tile [64][TSTRIDE] bf16.
__global__ __launch_bounds__(256) void fused_tail(const unsigned short* __restrict__ hpre,
                                                  const int* __restrict__ offsets,
                                                  const int* __restrict__ edge_src,
                                                  const unsigned short* __restrict__ Wt1,
                                                  const float* __restrict__ b1,
                                                  const unsigned short* __restrict__ Wt2,
                                                  const float* __restrict__ b2,
                                                  const float* __restrict__ gamma,
                                                  const float* __restrict__ beta,
                                                  float* __restrict__ out, int nN) {
    __shared__ unsigned short tile[64 * TSTRIDE];   // 17.4 KB
    const int t = threadIdx.x;
    const int wave = t >> 6, lane = t & 63;
    const int base = blockIdx.x * 64;

    // ---- Phase A: gather agg rows into LDS (fp32 accumulate, bf16 store) ----
    {
        const int sub = lane >> 4;   // 0..3: which node of the group of 4
        const int li = lane & 15;    // 16B chunk within row (8 bf16)
        for (int g = 0; g < 4; ++g) {
            const int local = wave * 16 + g * 4 + sub;
            const int nd = base + local;
            float a[8] = {0.f, 0.f, 0.f, 0.f, 0.f, 0.f, 0.f, 0.f};
            if (nd < nN) {
                const int beg = offsets[nd], end = offsets[nd + 1];
                for (int j = beg; j < end; ++j) {
                    const int s = edge_src[j];
                    bf16x8 v = *(const bf16x8*)(hpre + (size_t)s * D + li * 8);
#pragma unroll
                    for (int i = 0; i < 8; ++i) a[i] += bf2f((unsigned short)v[i]);
                }
            }
            bf16x8 p;
#pragma unroll
            for (int i = 0; i < 8; ++i) p[i] = (short)f2bf(a[i]);
            *(bf16x8*)(&tile[local * TSTRIDE + li * 8]) = p;
        }
    }
    __syncthreads();

    const int ml = lane & 15, q = lane >> 4;
    const int row = wave * 16 + ml;
    const int node = base + row;
    const int rr = (node < nN) ? node : (nN - 1);
    const bool ok = (node < nN);

    // ---- Phase B: t1 = relu(agg @ W1 + b1), written back into tile ----
    {
        bf16x8 bfrag[4];
#pragma unroll
        for (int kb = 0; kb < 4; ++kb)
            bfrag[kb] = *(const bf16x8*)(&tile[row * TSTRIDE + kb * 32 + q * 8]);
        float accs[8][4];
#pragma unroll
        for (int tl = 0; tl < 8; ++tl) {
            floatx4 acc = {0.f, 0.f, 0.f, 0.f};
            const unsigned short* wp = Wt1 + (size_t)(tl * 16 + ml) * D + q * 8;
#pragma unroll
            for (int kb = 0; kb < 4; ++kb) {
                bf16x8 af = *(const bf16x8*)(wp + kb * 32);
                acc = __builtin_amdgcn_mfma_f32_16x16x32_bf16(af, bfrag[kb], acc, 0, 0, 0);
            }
            const int f0i = tl * 16 + q * 4;
            float4 b4 = *(const float4*)(b1 + f0i);
            accs[tl][0] = fmaxf(acc[0] + b4.x, 0.f);
            accs[tl][1] = fmaxf(acc[1] + b4.y, 0.f);
            accs[tl][2] = fmaxf(acc[2] + b4.z, 0.f);
            accs[tl][3] = fmaxf(acc[3] + b4.w, 0.f);
        }
        __syncthreads();   // all reads of agg done before overwrite
#pragma unroll
        for (int tl = 0; tl < 8; ++tl) {
            ushort4 o;
            o.x = f2bf(accs[tl][0]); o.y = f2bf(accs[tl][1]);
            o.z = f2bf(accs[tl][2]); o.w = f2bf(accs[tl][3]);
            *(ushort4*)(&tile[row * TSTRIDE + tl * 16 + q * 4]) = o;
        }
    }
    __syncthreads();

    // ---- Phase C: out = LN(hpre + relu(t1 @ W2 + b2)) ----
    {
        bf16x8 bfrag[4];
#pragma unroll
        for (int kb = 0; kb < 4; ++kb)
            bfrag[kb] = *(const bf16x8*)(&tile[row * TSTRIDE + kb * 32 + q * 8]);

        float vs[8][4];
        float sm = 0.f, sq = 0.f;
#pragma unroll
        for (int tl = 0; tl < 8; ++tl) {
            floatx4 acc = {0.f, 0.f, 0.f, 0.f};
            const unsigned short* wp = Wt2 + (size_t)(tl * 16 + ml) * D + q * 8;
#pragma unroll
            for (int kb = 0; kb < 4; ++kb) {
                bf16x8 af = *(const bf16x8*)(wp + kb * 32);
                acc = __builtin_amdgcn_mfma_f32_16x16x32_bf16(af, bfrag[kb], acc, 0, 0, 0);
            }
            const int f0i = tl * 16 + q * 4;
            float4 b4 = *(const float4*)(b2 + f0i);
            ushort4 hr = ((const ushort4*)(hpre + (size_t)rr * D + f0i))[0];
            float a0 = fmaxf(acc[0] + b4.x, 0.f) + bf2f(hr.x);
            float a1 = fmaxf(acc[1] + b4.y, 0.f) + bf2f(hr.y);
            float a2 = fmaxf(acc[2] + b4.z, 0.f) + bf2f(hr.z);
            float a3 = fmaxf(acc[3] + b4.w, 0.f) + bf2f(hr.w);
            vs[tl][0] = a0; vs[tl][1] = a1; vs[tl][2] = a2; vs[tl][3] = a3;
            sm += a0 + a1 + a2 + a3;
            sq += a0 * a0 + a1 * a1 + a2 * a2 + a3 * a3;
        }

        sm += __shfl_xor(sm, 16); sm += __shfl_xor(sm, 32);
        sq += __shfl_xor(sq, 16); sq += __shfl_xor(sq, 32);

        const float mu = sm * (1.f / D);
        const float var = sq * (1.f / D) - mu * mu;
        const float is = rsqrtf(var + EPS);

        if (ok) {
#pragma unroll
            for (int tl = 0; tl < 8; ++tl) {
                const int f0i = tl * 16 + q * 4;
                float4 g4 = *(const float4*)(gamma + f0i);
                float4 be4 = *(const float4*)(beta + f0i);
                float4 o;
                o.x = (vs[tl][0] - mu) * is * g4.x + be4.x;
                o.y = (vs[tl][1] - mu) * is * g4.y + be4.y;
                o.z = (vs[tl][2] - mu) * is * g4.z + be4.z;
                o.w = (vs[tl][3] - mu) * is * g4.w + be4.w;
                *(float4*)(out + (size_t)node * D + f0i) = o;
            }
        }
    }
}

extern "C" void kernel_launch(void* const* d_in, const int* in_sizes, int n_in,
                              void* d_out, int out_size, void* d_ws, size_t ws_size,
                              hipStream_t stream) {
    const float* h     = (const float*)d_in[0];
    const int*   src   = (const int*)d_in[1];
    const int*   dst   = (const int*)d_in[2];
    const float* W_pre = (const float*)d_in[3];
    const float* b_pre = (const float*)d_in[4];
    const float* W1    = (const float*)d_in[5];
    const float* b1    = (const float*)d_in[6];
    const float* W2    = (const float*)d_in[7];
    const float* b2    = (const float*)d_in[8];
    const float* gamma = (const float*)d_in[9];
    const float* beta  = (const float*)d_in[10];
    float* out = (float*)d_out;

    const int nN = in_sizes[0] / D;   // 50000
    const int nE = in_sizes[1];       // 600000
    const size_t rowsz = (size_t)nN * D;

    // ---- workspace layout ----
    unsigned short* hpre = (unsigned short*)d_ws;      // [nN*D] bf16
    unsigned short* wt   = hpre + rowsz;               // [3*D*D] bf16
    int* edge_src  = (int*)(wt + 3 * D * D);           // [nE]
    int* offsets   = edge_src + nE;                    // [nN+1]
    int* cursor    = offsets + nN + 1;                 // [nN]
    int* counts    = cursor + nN;                      // [nN]
    int* chunkSums = counts + nN;                      // [64]

    const int prep_n  = (3 * D * D > nN) ? 3 * D * D : nN;
    const int eblocks = (nE + 255) / 256;
    const int gblocks = (nN + 63) / 64;
    const int nChunks = (nN + SCAN_CHUNK - 1) / SCAN_CHUNK;   // 49

    prep<<<(prep_n + 255) / 256, 256, 0, stream>>>(W_pre, W1, W2, wt, counts, nN);
    hist_dst<<<eblocks, 256, 0, stream>>>(dst, counts, nE);
    scan_chunk_sums<<<nChunks, 256, 0, stream>>>(counts, chunkSums, nN);
    scan_top<<<1, 64, 0, stream>>>(chunkSums, nChunks, offsets, nN, nE);
    scan_final<<<nChunks, 256, 0, stream>>>(counts, chunkSums, offsets, cursor, nN);
    fill_edges<<<eblocks, 256, 0, stream>>>(src, dst, cursor, edge_src, nE);

    gemm1<<<gblocks, 256, 0, stream>>>(h, wt, b_pre, hpre, nN);
    fused_tail<<<gblocks, 256, 0, stream>>>(hpre, offsets, edge_src,
                                            wt + D * D, b1, wt + 2 * D * D, b2,
                                            gamma, beta, out, nN);
}

// Round 5
// 243.915 us; speedup vs baseline: 1.5716x; 1.2282x over previous
//
#include <hip/hip_runtime.h>

#define D 128
#define EPS 1e-5f
#define SCAN_CHUNK 1024   // elements per scan block (256 thr x 4)
#define TSTRIDE 136       // LDS tile row stride in shorts (272 B = 17*16 -> 16B aligned, 2-way banks)

typedef __attribute__((ext_vector_type(8))) short bf16x8;
typedef __attribute__((ext_vector_type(4))) float floatx4;

// fp32 -> bf16 round-to-nearest-even
__device__ __forceinline__ unsigned short f2bf(float f) {
    union { float f; unsigned u; } v; v.f = f;
    unsigned r = v.u + 0x7fffu + ((v.u >> 16) & 1u);
    return (unsigned short)(r >> 16);
}
__device__ __forceinline__ float bf2f(unsigned short s) {
    union { unsigned u; float f; } v; v.u = ((unsigned)s) << 16; return v.f;
}

// ---------------- prep: transpose+convert 3 weight matrices to bf16 Wt[f][k]; zero counts ----
__global__ __launch_bounds__(256) void prep(const float* __restrict__ W0,
                                            const float* __restrict__ W1,
                                            const float* __restrict__ W2,
                                            unsigned short* __restrict__ wt,
                                            int* __restrict__ counts, int nN) {
    int idx = blockIdx.x * 256 + threadIdx.x;
    if (idx < 3 * D * D) {
        int w = idx >> 14;
        int r = idx & (D * D - 1);
        int f = r >> 7, k = r & (D - 1);
        const float* W = (w == 0) ? W0 : (w == 1) ? W1 : W2;
        wt[(size_t)w * D * D + (size_t)f * D + k] = f2bf(W[(size_t)k * D + f]);
    }
    if (idx < nN) counts[idx] = 0;
}

// ---------------- CSR build ----------------
__global__ __launch_bounds__(256) void hist_dst(const int* __restrict__ dst,
                                                int* __restrict__ counts, int nE) {
    int e = blockIdx.x * 256 + threadIdx.x;
    if (e < nE) atomicAdd(&counts[dst[e]], 1);
}

__global__ __launch_bounds__(256) void scan_chunk_sums(const int* __restrict__ counts,
                                                       int* __restrict__ chunkSums, int n) {
    __shared__ int sh[256];
    const int t = threadIdx.x;
    const int base = blockIdx.x * SCAN_CHUNK + t * 4;
    int s = 0;
#pragma unroll
    for (int i = 0; i < 4; ++i) {
        int idx = base + i;
        if (idx < n) s += counts[idx];
    }
    sh[t] = s;
    __syncthreads();
    for (int off = 128; off > 0; off >>= 1) {
        if (t < off) sh[t] += sh[t + off];
        __syncthreads();
    }
    if (t == 0) chunkSums[blockIdx.x] = sh[0];
}

__global__ __launch_bounds__(64) void scan_top(int* __restrict__ chunkSums, int nChunks,
                                               int* __restrict__ offsets, int nN, int nE) {
    const int t = threadIdx.x;
    int orig = (t < nChunks) ? chunkSums[t] : 0;
    int v = orig;
#pragma unroll
    for (int off = 1; off < 64; off <<= 1) {
        int u = __shfl_up(v, off, 64);
        if (t >= off) v += u;
    }
    if (t < nChunks) chunkSums[t] = v - orig;   // exclusive
    if (t == 0) offsets[nN] = nE;
}

__global__ __launch_bounds__(256) void scan_final(const int* __restrict__ counts,
                                                  const int* __restrict__ chunkSums,
                                                  int* __restrict__ offsets,
                                                  int* __restrict__ cursor, int n) {
    __shared__ int sh[256];
    const int t = threadIdx.x;
    const int base = blockIdx.x * SCAN_CHUNK + t * 4;
    int c[4];
    int s = 0;
#pragma unroll
    for (int i = 0; i < 4; ++i) {
        int idx = base + i;
        c[i] = (idx < n) ? counts[idx] : 0;
        s += c[i];
    }
    sh[t] = s;
    __syncthreads();
    int val = s;
    for (int off = 1; off < 256; off <<= 1) {
        int u = (t >= off) ? sh[t - off] : 0;
        __syncthreads();
        val += u;
        sh[t] = val;
        __syncthreads();
    }
    int run = val - s + chunkSums[blockIdx.x];
#pragma unroll
    for (int i = 0; i < 4; ++i) {
        int idx = base + i;
        if (idx < n) {
            offsets[idx] = run;
            cursor[idx] = run;
        }
        run += c[i];
    }
}

__global__ __launch_bounds__(256) void fill_edges(const int* __restrict__ src,
                                                  const int* __restrict__ dst,
                                                  int* __restrict__ cursor,
                                                  int* __restrict__ edge_src, int nE) {
    int e = blockIdx.x * 256 + threadIdx.x;
    if (e < nE) {
        int pos = atomicAdd(&cursor[dst[e]], 1);
        edge_src[pos] = src[e];
    }
}

// ---------------- GEMM1: hpre = h @ W_pre + b_pre (fp32 in, bf16 out) ----------------
__global__ __launch_bounds__(256) void gemm1(const float* __restrict__ X,
                                             const unsigned short* __restrict__ Wt,
                                             const float* __restrict__ bias,
                                             unsigned short* __restrict__ Y, int nrows) {
    const int t = threadIdx.x;
    const int lane = t & 63, wave = t >> 6;
    const int ml = lane & 15, q = lane >> 4;
    const int node = blockIdx.x * 64 + wave * 16 + ml;
    const int rr = (node < nrows) ? node : (nrows - 1);
    const bool ok = (node < nrows);

    bf16x8 bfrag[4];
    const float* xp = X + (size_t)rr * D + q * 8;
#pragma unroll
    for (int kb = 0; kb < 4; ++kb) {
        float4 f0 = *(const float4*)(xp + kb * 32);
        float4 f1 = *(const float4*)(xp + kb * 32 + 4);
        bf16x8 v;
        v[0] = (short)f2bf(f0.x); v[1] = (short)f2bf(f0.y);
        v[2] = (short)f2bf(f0.z); v[3] = (short)f2bf(f0.w);
        v[4] = (short)f2bf(f1.x); v[5] = (short)f2bf(f1.y);
        v[6] = (short)f2bf(f1.z); v[7] = (short)f2bf(f1.w);
        bfrag[kb] = v;
    }

#pragma unroll
    for (int tl = 0; tl < 8; ++tl) {
        floatx4 acc = {0.f, 0.f, 0.f, 0.f};
        const unsigned short* wp = Wt + (size_t)(tl * 16 + ml) * D + q * 8;
#pragma unroll
        for (int kb = 0; kb < 4; ++kb) {
            bf16x8 af = *(const bf16x8*)(wp + kb * 32);
            acc = __builtin_amdgcn_mfma_f32_16x16x32_bf16(af, bfrag[kb], acc, 0, 0, 0);
        }
        const int f0i = tl * 16 + q * 4;
        float4 b4 = *(const float4*)(bias + f0i);
        if (ok) {
            ushort4 o;
            o.x = f2bf(acc[0] + b4.x); o.y = f2bf(acc[1] + b4.y);
            o.z = f2bf(acc[2] + b4.z); o.w = f2bf(acc[3] + b4.w);
            *(ushort4*)(Y + (size_t)node * D + f0i) = o;
        }
    }
}

// ---------------- gather segment-sum: agg[n] = sum hpre[edge_src[j]] (bf16, fp32 acc) -----
// 16 lanes per node (16B/lane), 16 nodes per 256-thread block -> 50000 concurrent streams.
// Unroll-2 over edges with 2-ahead index prefetch: 2 independent row loads in flight.
__global__ __launch_bounds__(256) void gather_sum(const unsigned short* __restrict__ hpre,
                                                  const int* __restrict__ offsets,
                                                  const int* __restrict__ edge_src,
                                                  unsigned short* __restrict__ agg, int nN) {
    const int t = threadIdx.x;
    const int li = t & 15;
    const int n = blockIdx.x * 16 + (t >> 4);
    if (n >= nN) return;
    const int beg = offsets[n], end = offsets[n + 1];

    float a[8] = {0.f, 0.f, 0.f, 0.f, 0.f, 0.f, 0.f, 0.f};
    int j = beg;
    int s0 = 0, s1 = 0;
    if (j < end) s0 = edge_src[j];
    if (j + 1 < end) s1 = edge_src[j + 1];

    while (j + 1 < end) {
        const int c0 = s0, c1 = s1;
        const int jn = j + 2;
        if (jn < end) s0 = edge_src[jn];                 // prefetch next pair
        if (jn + 1 < end) s1 = edge_src[jn + 1];
        bf16x8 v0 = *(const bf16x8*)(hpre + (size_t)c0 * D + li * 8);
        bf16x8 v1 = *(const bf16x8*)(hpre + (size_t)c1 * D + li * 8);
#pragma unroll
        for (int i = 0; i < 8; ++i)
            a[i] += bf2f((unsigned short)v0[i]) + bf2f((unsigned short)v1[i]);
        j = jn;
    }
    if (j < end) {                                       // odd remainder (index already in s0)
        bf16x8 v0 = *(const bf16x8*)(hpre + (size_t)s0 * D + li * 8);
#pragma unroll
        for (int i = 0; i < 8; ++i) a[i] += bf2f((unsigned short)v0[i]);
    }

    bf16x8 p;
#pragma unroll
    for (int i = 0; i < 8; ++i) p[i] = (short)f2bf(a[i]);
    *(bf16x8*)(agg + (size_t)n * D + li * 8) = p;
}

// ---------------- fused MLP: GEMM2(relu) -> GEMM3 -> +res -> LayerNorm ----------------
// Block = 256 threads = 4 waves = 64 nodes. GEMM2 B-frag read directly from global agg;
// LDS tile only for the t1 C-layout -> B-layout transform (one barrier).
__global__ __launch_bounds__(256) void fused_mlp(const unsigned short* __restrict__ agg,
                                                 const unsigned short* __restrict__ hpre,
                                                 const unsigned short* __restrict__ Wt1,
                                                 const float* __restrict__ b1,
                                                 const unsigned short* __restrict__ Wt2,
                                                 const float* __restrict__ b2,
                                                 const float* __restrict__ gamma,
                                                 const float* __restrict__ beta,
                                                 float* __restrict__ out, int nN) {
    __shared__ unsigned short tile[64 * TSTRIDE];   // 17.4 KB
    const int t = threadIdx.x;
    const int wave = t >> 6, lane = t & 63;
    const int ml = lane & 15, q = lane >> 4;
    const int row = wave * 16 + ml;
    const int node = blockIdx.x * 64 + row;
    const int rr = (node < nN) ? node : (nN - 1);
    const bool ok = (node < nN);

    // ---- GEMM2: t1 = relu(agg @ W1 + b1) -> LDS tile (C-layout write) ----
    {
        bf16x8 bfrag[4];
        const unsigned short* xp = agg + (size_t)rr * D + q * 8;
#pragma unroll
        for (int kb = 0; kb < 4; ++kb) bfrag[kb] = *(const bf16x8*)(xp + kb * 32);

        float accs[8][4];
#pragma unroll
        for (int tl = 0; tl < 8; ++tl) {
            floatx4 acc = {0.f, 0.f, 0.f, 0.f};
            const unsigned short* wp = Wt1 + (size_t)(tl * 16 + ml) * D + q * 8;
#pragma unroll
            for (int kb = 0; kb < 4; ++kb) {
                bf16x8 af = *(const bf16x8*)(wp + kb * 32);
                acc = __builtin_amdgcn_mfma_f32_16x16x32_bf16(af, bfrag[kb], acc, 0, 0, 0);
            }
            const int f0i = tl * 16 + q * 4;
            float4 b4 = *(const float4*)(b1 + f0i);
            accs[tl][0] = fmaxf(acc[0] + b4.x, 0.f);
            accs[tl][1] = fmaxf(acc[1] + b4.y, 0.f);
            accs[tl][2] = fmaxf(acc[2] + b4.z, 0.f);
            accs[tl][3] = fmaxf(acc[3] + b4.w, 0.f);
        }
#pragma unroll
        for (int tl = 0; tl < 8; ++tl) {
            ushort4 o;
            o.x = f2bf(accs[tl][0]); o.y = f2bf(accs[tl][1]);
            o.z = f2bf(accs[tl][2]); o.w = f2bf(accs[tl][3]);
            *(ushort4*)(&tile[row * TSTRIDE + tl * 16 + q * 4]) = o;
        }
    }
    __syncthreads();

    // ---- GEMM3 + residual + LayerNorm ----
    {
        bf16x8 bfrag[4];
#pragma unroll
        for (int kb = 0; kb < 4; ++kb)
            bfrag[kb] = *(const bf16x8*)(&tile[row * TSTRIDE + kb * 32 + q * 8]);

        float vs[8][4];
        float sm = 0.f, sq = 0.f;
#pragma unroll
        for (int tl = 0; tl < 8; ++tl) {
            floatx4 acc = {0.f, 0.f, 0.f, 0.f};
            const unsigned short* wp = Wt2 + (size_t)(tl * 16 + ml) * D + q * 8;
#pragma unroll
            for (int kb = 0; kb < 4; ++kb) {
                bf16x8 af = *(const bf16x8*)(wp + kb * 32);
                acc = __builtin_amdgcn_mfma_f32_16x16x32_bf16(af, bfrag[kb], acc, 0, 0, 0);
            }
            const int f0i = tl * 16 + q * 4;
            float4 b4 = *(const float4*)(b2 + f0i);
            ushort4 hr = ((const ushort4*)(hpre + (size_t)rr * D + f0i))[0];
            float a0 = fmaxf(acc[0] + b4.x, 0.f) + bf2f(hr.x);
            float a1 = fmaxf(acc[1] + b4.y, 0.f) + bf2f(hr.y);
            float a2 = fmaxf(acc[2] + b4.z, 0.f) + bf2f(hr.z);
            float a3 = fmaxf(acc[3] + b4.w, 0.f) + bf2f(hr.w);
            vs[tl][0] = a0; vs[tl][1] = a1; vs[tl][2] = a2; vs[tl][3] = a3;
            sm += a0 + a1 + a2 + a3;
            sq += a0 * a0 + a1 * a1 + a2 * a2 + a3 * a3;
        }

        sm += __shfl_xor(sm, 16); sm += __shfl_xor(sm, 32);
        sq += __shfl_xor(sq, 16); sq += __shfl_xor(sq, 32);

        const float mu = sm * (1.f / D);
        const float var = sq * (1.f / D) - mu * mu;
        const float is = rsqrtf(var + EPS);

        if (ok) {
#pragma unroll
            for (int tl = 0; tl < 8; ++tl) {
                const int f0i = tl * 16 + q * 4;
                float4 g4 = *(const float4*)(gamma + f0i);
                float4 be4 = *(const float4*)(beta + f0i);
                float4 o;
                o.x = (vs[tl][0] - mu) * is * g4.x + be4.x;
                o.y = (vs[tl][1] - mu) * is * g4.y + be4.y;
                o.z = (vs[tl][2] - mu) * is * g4.z + be4.z;
                o.w = (vs[tl][3] - mu) * is * g4.w + be4.w;
                *(float4*)(out + (size_t)node * D + f0i) = o;
            }
        }
    }
}

extern "C" void kernel_launch(void* const* d_in, const int* in_sizes, int n_in,
                              void* d_out, int out_size, void* d_ws, size_t ws_size,
                              hipStream_t stream) {
    const float* h     = (const float*)d_in[0];
    const int*   src   = (const int*)d_in[1];
    const int*   dst   = (const int*)d_in[2];
    const float* W_pre = (const float*)d_in[3];
    const float* b_pre = (const float*)d_in[4];
    const float* W1    = (const float*)d_in[5];
    const float* b1    = (const float*)d_in[6];
    const float* W2    = (const float*)d_in[7];
    const float* b2    = (const float*)d_in[8];
    const float* gamma = (const float*)d_in[9];
    const float* beta  = (const float*)d_in[10];
    float* out = (float*)d_out;

    const int nN = in_sizes[0] / D;   // 50000
    const int nE = in_sizes[1];       // 600000
    const size_t rowsz = (size_t)nN * D;

    // ---- workspace layout ----
    unsigned short* hpre = (unsigned short*)d_ws;      // [nN*D] bf16
    unsigned short* agg  = hpre + rowsz;               // [nN*D] bf16
    unsigned short* wt   = agg + rowsz;                // [3*D*D] bf16
    int* edge_src  = (int*)(wt + 3 * D * D);           // [nE]
    int* offsets   = edge_src + nE;                    // [nN+1]
    int* cursor    = offsets + nN + 1;                 // [nN]
    int* counts    = cursor + nN;                      // [nN]
    int* chunkSums = counts + nN;                      // [64]

    const int prep_n  = (3 * D * D > nN) ? 3 * D * D : nN;
    const int eblocks = (nE + 255) / 256;
    const int gblocks = (nN + 63) / 64;
    const int nChunks = (nN + SCAN_CHUNK - 1) / SCAN_CHUNK;   // 49

    prep<<<(prep_n + 255) / 256, 256, 0, stream>>>(W_pre, W1, W2, wt, counts, nN);
    hist_dst<<<eblocks, 256, 0, stream>>>(dst, counts, nE);
    scan_chunk_sums<<<nChunks, 256, 0, stream>>>(counts, chunkSums, nN);
    scan_top<<<1, 64, 0, stream>>>(chunkSums, nChunks, offsets, nN, nE);
    scan_final<<<nChunks, 256, 0, stream>>>(counts, chunkSums, offsets, cursor, nN);
    fill_edges<<<eblocks, 256, 0, stream>>>(src, dst, cursor, edge_src, nE);

    gemm1<<<gblocks, 256, 0, stream>>>(h, wt, b_pre, hpre, nN);
    gather_sum<<<(nN + 15) / 16, 256, 0, stream>>>(hpre, offsets, edge_src, agg, nN);
    fused_mlp<<<gblocks, 256, 0, stream>>>(agg, hpre, wt + D * D, b1, wt + 2 * D * D, b2,
                                           gamma, beta, out, nN);
}

// Round 6
// 243.321 us; speedup vs baseline: 1.5754x; 1.0024x over previous
//
#include <hip/hip_runtime.h>

#define D 128
#define EPS 1e-5f
#define SCAN_CHUNK 1024   // elements per scan block (256 thr x 4)
#define TSTRIDE 136       // LDS tile row stride in shorts (272 B = 17*16 -> 16B aligned, 2-way banks)

typedef __attribute__((ext_vector_type(8))) short bf16x8;
typedef __attribute__((ext_vector_type(4))) float floatx4;

// fp32 -> bf16 round-to-nearest-even
__device__ __forceinline__ unsigned short f2bf(float f) {
    union { float f; unsigned u; } v; v.f = f;
    unsigned r = v.u + 0x7fffu + ((v.u >> 16) & 1u);
    return (unsigned short)(r >> 16);
}
__device__ __forceinline__ float bf2f(unsigned short s) {
    union { unsigned u; float f; } v; v.u = ((unsigned)s) << 16; return v.f;
}

// ---------------- prep: transpose+convert 3 weight matrices to bf16 Wt[f][k]; zero counts ----
__global__ __launch_bounds__(256) void prep(const float* __restrict__ W0,
                                            const float* __restrict__ W1,
                                            const float* __restrict__ W2,
                                            unsigned short* __restrict__ wt,
                                            int* __restrict__ counts, int nN) {
    int idx = blockIdx.x * 256 + threadIdx.x;
    if (idx < 3 * D * D) {
        int w = idx >> 14;
        int r = idx & (D * D - 1);
        int f = r >> 7, k = r & (D - 1);
        const float* W = (w == 0) ? W0 : (w == 1) ? W1 : W2;
        wt[(size_t)w * D * D + (size_t)f * D + k] = f2bf(W[(size_t)k * D + f]);
    }
    if (idx < nN) counts[idx] = 0;
}

// ---------------- CSR build ----------------
__global__ __launch_bounds__(256) void hist_dst(const int* __restrict__ dst,
                                                int* __restrict__ counts, int nE) {
    int e = blockIdx.x * 256 + threadIdx.x;
    if (e < nE) atomicAdd(&counts[dst[e]], 1);
}

__global__ __launch_bounds__(256) void scan_chunk_sums(const int* __restrict__ counts,
                                                       int* __restrict__ chunkSums, int n) {
    __shared__ int sh[256];
    const int t = threadIdx.x;
    const int base = blockIdx.x * SCAN_CHUNK + t * 4;
    int s = 0;
#pragma unroll
    for (int i = 0; i < 4; ++i) {
        int idx = base + i;
        if (idx < n) s += counts[idx];
    }
    sh[t] = s;
    __syncthreads();
    for (int off = 128; off > 0; off >>= 1) {
        if (t < off) sh[t] += sh[t + off];
        __syncthreads();
    }
    if (t == 0) chunkSums[blockIdx.x] = sh[0];
}

__global__ __launch_bounds__(64) void scan_top(int* __restrict__ chunkSums, int nChunks,
                                               int* __restrict__ offsets, int nN, int nE) {
    const int t = threadIdx.x;
    int orig = (t < nChunks) ? chunkSums[t] : 0;
    int v = orig;
#pragma unroll
    for (int off = 1; off < 64; off <<= 1) {
        int u = __shfl_up(v, off, 64);
        if (t >= off) v += u;
    }
    if (t < nChunks) chunkSums[t] = v - orig;   // exclusive
    if (t == 0) offsets[nN] = nE;
}

__global__ __launch_bounds__(256) void scan_final(const int* __restrict__ counts,
                                                  const int* __restrict__ chunkSums,
                                                  int* __restrict__ offsets,
                                                  int* __restrict__ cursor, int n) {
    __shared__ int sh[256];
    const int t = threadIdx.x;
    const int base = blockIdx.x * SCAN_CHUNK + t * 4;
    int c[4];
    int s = 0;
#pragma unroll
    for (int i = 0; i < 4; ++i) {
        int idx = base + i;
        c[i] = (idx < n) ? counts[idx] : 0;
        s += c[i];
    }
    sh[t] = s;
    __syncthreads();
    int val = s;
    for (int off = 1; off < 256; off <<= 1) {
        int u = (t >= off) ? sh[t - off] : 0;
        __syncthreads();
        val += u;
        sh[t] = val;
        __syncthreads();
    }
    int run = val - s + chunkSums[blockIdx.x];
#pragma unroll
    for (int i = 0; i < 4; ++i) {
        int idx = base + i;
        if (idx < n) {
            offsets[idx] = run;
            cursor[idx] = run;
        }
        run += c[i];
    }
}

__global__ __launch_bounds__(256) void fill_edges(const int* __restrict__ src,
                                                  const int* __restrict__ dst,
                                                  int* __restrict__ cursor,
                                                  int* __restrict__ edge_src, int nE) {
    int e = blockIdx.x * 256 + threadIdx.x;
    if (e < nE) {
        int pos = atomicAdd(&cursor[dst[e]], 1);
        edge_src[pos] = src[e];
    }
}

// ---------------- GEMM1: hpre = h @ W_pre + b_pre (fp32 in, bf16 out) ----------------
// Block = 4 waves = 32 nodes: 2 groups x 16 nodes, each group served by 2 waves
// (hf = which half of the 8 output tiles). 2x waves vs R5 -> latency hiding.
__global__ __launch_bounds__(256) void gemm1(const float* __restrict__ X,
                                             const unsigned short* __restrict__ Wt,
                                             const float* __restrict__ bias,
                                             unsigned short* __restrict__ Y, int nrows) {
    const int t = threadIdx.x;
    const int lane = t & 63, wave = t >> 6;
    const int g = wave >> 1, hf = wave & 1;
    const int ml = lane & 15, q = lane >> 4;
    const int node = blockIdx.x * 32 + g * 16 + ml;
    const int rr = (node < nrows) ? node : (nrows - 1);
    const bool ok = (node < nrows);

    bf16x8 bfrag[4];
    const float* xp = X + (size_t)rr * D + q * 8;
#pragma unroll
    for (int kb = 0; kb < 4; ++kb) {
        float4 f0 = *(const float4*)(xp + kb * 32);
        float4 f1 = *(const float4*)(xp + kb * 32 + 4);
        bf16x8 v;
        v[0] = (short)f2bf(f0.x); v[1] = (short)f2bf(f0.y);
        v[2] = (short)f2bf(f0.z); v[3] = (short)f2bf(f0.w);
        v[4] = (short)f2bf(f1.x); v[5] = (short)f2bf(f1.y);
        v[6] = (short)f2bf(f1.z); v[7] = (short)f2bf(f1.w);
        bfrag[kb] = v;
    }

#pragma unroll
    for (int tl2 = 0; tl2 < 4; ++tl2) {
        const int tl = hf * 4 + tl2;
        floatx4 acc = {0.f, 0.f, 0.f, 0.f};
        const unsigned short* wp = Wt + (size_t)(tl * 16 + ml) * D + q * 8;
#pragma unroll
        for (int kb = 0; kb < 4; ++kb) {
            bf16x8 af = *(const bf16x8*)(wp + kb * 32);
            acc = __builtin_amdgcn_mfma_f32_16x16x32_bf16(af, bfrag[kb], acc, 0, 0, 0);
        }
        const int f0i = tl * 16 + q * 4;
        float4 b4 = *(const float4*)(bias + f0i);
        if (ok) {
            ushort4 o;
            o.x = f2bf(acc[0] + b4.x); o.y = f2bf(acc[1] + b4.y);
            o.z = f2bf(acc[2] + b4.z); o.w = f2bf(acc[3] + b4.w);
            *(ushort4*)(Y + (size_t)node * D + f0i) = o;
        }
    }
}

// ---------------- gather segment-sum: agg[n] = sum hpre[edge_src[j]] (bf16, fp32 acc) -----
__global__ __launch_bounds__(256) void gather_sum(const unsigned short* __restrict__ hpre,
                                                  const int* __restrict__ offsets,
                                                  const int* __restrict__ edge_src,
                                                  unsigned short* __restrict__ agg, int nN) {
    const int t = threadIdx.x;
    const int li = t & 15;
    const int n = blockIdx.x * 16 + (t >> 4);
    if (n >= nN) return;
    const int beg = offsets[n], end = offsets[n + 1];

    float a[8] = {0.f, 0.f, 0.f, 0.f, 0.f, 0.f, 0.f, 0.f};
    int j = beg;
    int s0 = 0, s1 = 0;
    if (j < end) s0 = edge_src[j];
    if (j + 1 < end) s1 = edge_src[j + 1];

    while (j + 1 < end) {
        const int c0 = s0, c1 = s1;
        const int jn = j + 2;
        if (jn < end) s0 = edge_src[jn];
        if (jn + 1 < end) s1 = edge_src[jn + 1];
        bf16x8 v0 = *(const bf16x8*)(hpre + (size_t)c0 * D + li * 8);
        bf16x8 v1 = *(const bf16x8*)(hpre + (size_t)c1 * D + li * 8);
#pragma unroll
        for (int i = 0; i < 8; ++i)
            a[i] += bf2f((unsigned short)v0[i]) + bf2f((unsigned short)v1[i]);
        j = jn;
    }
    if (j < end) {
        bf16x8 v0 = *(const bf16x8*)(hpre + (size_t)s0 * D + li * 8);
#pragma unroll
        for (int i = 0; i < 8; ++i) a[i] += bf2f((unsigned short)v0[i]);
    }

    bf16x8 p;
#pragma unroll
    for (int i = 0; i < 8; ++i) p[i] = (short)f2bf(a[i]);
    *(bf16x8*)(agg + (size_t)n * D + li * 8) = p;
}

// ---------------- fused MLP: GEMM2(relu) -> GEMM3 -> +res -> LayerNorm ----------------
// Block = 4 waves = 32 nodes (2 groups x 16), each group served by 2 waves (tile halves).
// t1 goes through an LDS tile; LN sums combined across the wave pair via LDS.
__global__ __launch_bounds__(256) void fused_mlp(const unsigned short* __restrict__ agg,
                                                 const unsigned short* __restrict__ hpre,
                                                 const unsigned short* __restrict__ Wt1,
                                                 const float* __restrict__ b1,
                                                 const unsigned short* __restrict__ Wt2,
                                                 const float* __restrict__ b2,
                                                 const float* __restrict__ gamma,
                                                 const float* __restrict__ beta,
                                                 float* __restrict__ out, int nN) {
    __shared__ unsigned short tile[32 * TSTRIDE];   // 8.7 KB
    __shared__ float psm[2][32], psq[2][32];        // per-half LN partials
    const int t = threadIdx.x;
    const int lane = t & 63, wave = t >> 6;
    const int g = wave >> 1, hf = wave & 1;
    const int ml = lane & 15, q = lane >> 4;
    const int lr = g * 16 + ml;                     // local row 0..31
    const int node = blockIdx.x * 32 + lr;
    const int rr = (node < nN) ? node : (nN - 1);
    const bool ok = (node < nN);

    // ---- GEMM2 (half): t1 features hf*64..hf*64+63 -> LDS tile ----
    {
        bf16x8 bfrag[4];
        const unsigned short* xp = agg + (size_t)rr * D + q * 8;
#pragma unroll
        for (int kb = 0; kb < 4; ++kb) bfrag[kb] = *(const bf16x8*)(xp + kb * 32);

#pragma unroll
        for (int tl2 = 0; tl2 < 4; ++tl2) {
            const int tl = hf * 4 + tl2;
            floatx4 acc = {0.f, 0.f, 0.f, 0.f};
            const unsigned short* wp = Wt1 + (size_t)(tl * 16 + ml) * D + q * 8;
#pragma unroll
            for (int kb = 0; kb < 4; ++kb) {
                bf16x8 af = *(const bf16x8*)(wp + kb * 32);
                acc = __builtin_amdgcn_mfma_f32_16x16x32_bf16(af, bfrag[kb], acc, 0, 0, 0);
            }
            const int f0i = tl * 16 + q * 4;
            float4 b4 = *(const float4*)(b1 + f0i);
            ushort4 o;
            o.x = f2bf(fmaxf(acc[0] + b4.x, 0.f));
            o.y = f2bf(fmaxf(acc[1] + b4.y, 0.f));
            o.z = f2bf(fmaxf(acc[2] + b4.z, 0.f));
            o.w = f2bf(fmaxf(acc[3] + b4.w, 0.f));
            *(ushort4*)(&tile[lr * TSTRIDE + f0i]) = o;
        }
    }
    __syncthreads();

    // ---- GEMM3 (half) + residual; partial LN sums ----
    float vs[4][4];
    float sm = 0.f, sq = 0.f;
    {
        bf16x8 bfrag[4];
#pragma unroll
        for (int kb = 0; kb < 4; ++kb)
            bfrag[kb] = *(const bf16x8*)(&tile[lr * TSTRIDE + kb * 32 + q * 8]);

#pragma unroll
        for (int tl2 = 0; tl2 < 4; ++tl2) {
            const int tl = hf * 4 + tl2;
            floatx4 acc = {0.f, 0.f, 0.f, 0.f};
            const unsigned short* wp = Wt2 + (size_t)(tl * 16 + ml) * D + q * 8;
#pragma unroll
            for (int kb = 0; kb < 4; ++kb) {
                bf16x8 af = *(const bf16x8*)(wp + kb * 32);
                acc = __builtin_amdgcn_mfma_f32_16x16x32_bf16(af, bfrag[kb], acc, 0, 0, 0);
            }
            const int f0i = tl * 16 + q * 4;
            float4 b4 = *(const float4*)(b2 + f0i);
            ushort4 hr = ((const ushort4*)(hpre + (size_t)rr * D + f0i))[0];
            float a0 = fmaxf(acc[0] + b4.x, 0.f) + bf2f(hr.x);
            float a1 = fmaxf(acc[1] + b4.y, 0.f) + bf2f(hr.y);
            float a2 = fmaxf(acc[2] + b4.z, 0.f) + bf2f(hr.z);
            float a3 = fmaxf(acc[3] + b4.w, 0.f) + bf2f(hr.w);
            vs[tl2][0] = a0; vs[tl2][1] = a1; vs[tl2][2] = a2; vs[tl2][3] = a3;
            sm += a0 + a1 + a2 + a3;
            sq += a0 * a0 + a1 * a1 + a2 * a2 + a3 * a3;
        }
        // reduce over quads -> this wave's partial (64 features) for node ml
        sm += __shfl_xor(sm, 16); sm += __shfl_xor(sm, 32);
        sq += __shfl_xor(sq, 16); sq += __shfl_xor(sq, 32);
        if (lane < 16) { psm[hf][lr] = sm; psq[hf][lr] = sq; }
    }
    __syncthreads();

    // ---- combine halves, normalize, write ----
    {
        const float smT = psm[0][lr] + psm[1][lr];
        const float sqT = psq[0][lr] + psq[1][lr];
        const float mu = smT * (1.f / D);
        const float var = sqT * (1.f / D) - mu * mu;
        const float is = rsqrtf(var + EPS);

        if (ok) {
#pragma unroll
            for (int tl2 = 0; tl2 < 4; ++tl2) {
                const int f0i = (hf * 4 + tl2) * 16 + q * 4;
                float4 g4 = *(const float4*)(gamma + f0i);
                float4 be4 = *(const float4*)(beta + f0i);
                float4 o;
                o.x = (vs[tl2][0] - mu) * is * g4.x + be4.x;
                o.y = (vs[tl2][1] - mu) * is * g4.y + be4.y;
                o.z = (vs[tl2][2] - mu) * is * g4.z + be4.z;
                o.w = (vs[tl2][3] - mu) * is * g4.w + be4.w;
                *(float4*)(out + (size_t)node * D + f0i) = o;
            }
        }
    }
}

extern "C" void kernel_launch(void* const* d_in, const int* in_sizes, int n_in,
                              void* d_out, int out_size, void* d_ws, size_t ws_size,
                              hipStream_t stream) {
    const float* h     = (const float*)d_in[0];
    const int*   src   = (const int*)d_in[1];
    const int*   dst   = (const int*)d_in[2];
    const float* W_pre = (const float*)d_in[3];
    const float* b_pre = (const float*)d_in[4];
    const float* W1    = (const float*)d_in[5];
    const float* b1    = (const float*)d_in[6];
    const float* W2    = (const float*)d_in[7];
    const float* b2    = (const float*)d_in[8];
    const float* gamma = (const float*)d_in[9];
    const float* beta  = (const float*)d_in[10];
    float* out = (float*)d_out;

    const int nN = in_sizes[0] / D;   // 50000
    const int nE = in_sizes[1];       // 600000
    const size_t rowsz = (size_t)nN * D;

    // ---- workspace layout ----
    unsigned short* hpre = (unsigned short*)d_ws;      // [nN*D] bf16
    unsigned short* agg  = hpre + rowsz;               // [nN*D] bf16
    unsigned short* wt   = agg + rowsz;                // [3*D*D] bf16
    int* edge_src  = (int*)(wt + 3 * D * D);           // [nE]
    int* offsets   = edge_src + nE;                    // [nN+1]
    int* cursor    = offsets + nN + 1;                 // [nN]
    int* counts    = cursor + nN;                      // [nN]
    int* chunkSums = counts + nN;                      // [64]

    const int prep_n  = (3 * D * D > nN) ? 3 * D * D : nN;
    const int eblocks = (nE + 255) / 256;
    const int gblocks = (nN + 31) / 32;    // 32 nodes per block now
    const int nChunks = (nN + SCAN_CHUNK - 1) / SCAN_CHUNK;   // 49

    prep<<<(prep_n + 255) / 256, 256, 0, stream>>>(W_pre, W1, W2, wt, counts, nN);
    hist_dst<<<eblocks, 256, 0, stream>>>(dst, counts, nE);
    scan_chunk_sums<<<nChunks, 256, 0, stream>>>(counts, chunkSums, nN);
    scan_top<<<1, 64, 0, stream>>>(chunkSums, nChunks, offsets, nN, nE);
    scan_final<<<nChunks, 256, 0, stream>>>(counts, chunkSums, offsets, cursor, nN);
    fill_edges<<<eblocks, 256, 0, stream>>>(src, dst, cursor, edge_src, nE);

    gemm1<<<gblocks, 256, 0, stream>>>(h, wt, b_pre, hpre, nN);
    gather_sum<<<(nN + 15) / 16, 256, 0, stream>>>(hpre, offsets, edge_src, agg, nN);
    fused_mlp<<<gblocks, 256, 0, stream>>>(agg, hpre, wt + D * D, b1, wt + 2 * D * D, b2,
                                           gamma, beta, out, nN);
}

// Round 9
// 227.461 us; speedup vs baseline: 1.6852x; 1.0697x over previous
//
#include <hip/hip_runtime.h>

#define D 128
#define EPS 1e-5f
#define SCAN_CHUNK 1024   // elements per scan block (256 thr x 4)
#define TSTRIDE 136       // LDS tile row stride in shorts (272 B = 17*16 -> 16B aligned, 2-way banks)

typedef __attribute__((ext_vector_type(8))) short bf16x8;
typedef __attribute__((ext_vector_type(4))) float floatx4;

// fp32 -> bf16 round-to-nearest-even
__device__ __forceinline__ unsigned short f2bf(float f) {
    union { float f; unsigned u; } v; v.f = f;
    unsigned r = v.u + 0x7fffu + ((v.u >> 16) & 1u);
    return (unsigned short)(r >> 16);
}
__device__ __forceinline__ float bf2f(unsigned short s) {
    union { unsigned u; float f; } v; v.u = ((unsigned)s) << 16; return v.f;
}

// ---------------- prep: weights -> bf16 Wt[f][k]; zero counts; offsets[nN]=nE ----------------
__global__ __launch_bounds__(256) void prep(const float* __restrict__ W0,
                                            const float* __restrict__ W1,
                                            const float* __restrict__ W2,
                                            unsigned short* __restrict__ wt,
                                            int* __restrict__ counts,
                                            int* __restrict__ offsets, int nN, int nE) {
    int idx = blockIdx.x * 256 + threadIdx.x;
    if (idx < 3 * D * D) {
        int w = idx >> 14;
        int r = idx & (D * D - 1);
        int f = r >> 7, k = r & (D - 1);
        const float* W = (w == 0) ? W0 : (w == 1) ? W1 : W2;
        wt[(size_t)w * D * D + (size_t)f * D + k] = f2bf(W[(size_t)k * D + f]);
    }
    if (idx < nN) counts[idx] = 0;
    if (idx == 0) offsets[nN] = nE;
}

// ---------------- CSR build ----------------
__global__ __launch_bounds__(256) void hist_dst(const int* __restrict__ dst,
                                                int* __restrict__ counts, int nE) {
    int e = blockIdx.x * 256 + threadIdx.x;
    if (e < nE) atomicAdd(&counts[dst[e]], 1);
}

__global__ __launch_bounds__(256) void scan_chunk_sums(const int* __restrict__ counts,
                                                       int* __restrict__ chunkSums, int n) {
    __shared__ int sh[256];
    const int t = threadIdx.x;
    const int base = blockIdx.x * SCAN_CHUNK + t * 4;
    int s = 0;
#pragma unroll
    for (int i = 0; i < 4; ++i) {
        int idx = base + i;
        if (idx < n) s += counts[idx];
    }
    sh[t] = s;
    __syncthreads();
    for (int off = 128; off > 0; off >>= 1) {
        if (t < off) sh[t] += sh[t + off];
        __syncthreads();
    }
    if (t == 0) chunkSums[blockIdx.x] = sh[0];
}

// per-chunk scan; each block re-derives its chunk base from chunkSums via a 64-lane scan
__global__ __launch_bounds__(256) void scan_final(const int* __restrict__ counts,
                                                  const int* __restrict__ chunkSums,
                                                  int nChunks,
                                                  int* __restrict__ offsets,
                                                  int* __restrict__ cursor, int n) {
    __shared__ int sh[256];
    __shared__ int sbase;
    const int t = threadIdx.x;
    if (t < 64) {
        int orig = (t < nChunks) ? chunkSums[t] : 0;
        int v = orig;
#pragma unroll
        for (int off = 1; off < 64; off <<= 1) {
            int u = __shfl_up(v, off, 64);
            if (t >= off) v += u;
        }
        if (t == blockIdx.x) sbase = v - orig;   // exclusive prefix for this chunk
    }
    const int base = blockIdx.x * SCAN_CHUNK + t * 4;
    int c[4];
    int s = 0;
#pragma unroll
    for (int i = 0; i < 4; ++i) {
        int idx = base + i;
        c[i] = (idx < n) ? counts[idx] : 0;
        s += c[i];
    }
    sh[t] = s;
    __syncthreads();
    int val = s;
    for (int off = 1; off < 256; off <<= 1) {
        int u = (t >= off) ? sh[t - off] : 0;
        __syncthreads();
        val += u;
        sh[t] = val;
        __syncthreads();
    }
    int run = val - s + sbase;
#pragma unroll
    for (int i = 0; i < 4; ++i) {
        int idx = base + i;
        if (idx < n) {
            offsets[idx] = run;
            cursor[idx] = run;
        }
        run += c[i];
    }
}

__global__ __launch_bounds__(256) void fill_edges(const int* __restrict__ src,
                                                  const int* __restrict__ dst,
                                                  int* __restrict__ cursor,
                                                  int* __restrict__ edge_src, int nE) {
    int e = blockIdx.x * 256 + threadIdx.x;
    if (e < nE) {
        int pos = atomicAdd(&cursor[dst[e]], 1);
        edge_src[pos] = src[e];
    }
}

// ---------------- GEMM1: hpre = h @ W_pre + b_pre (fp32 in, bf16 out) ----------------
// Block = 4 waves = 64 nodes. Wave(g,hf): nodes g*32+ml and g*32+16+ml (2 B-frags sharing
// each A-load -> 2 independent MFMA chains per weight load), tile half hf.
__global__ __launch_bounds__(256) void gemm1(const float* __restrict__ X,
                                             const unsigned short* __restrict__ Wt,
                                             const float* __restrict__ bias,
                                             unsigned short* __restrict__ Y, int nrows) {
    const int t = threadIdx.x;
    const int lane = t & 63, wave = t >> 6;
    const int g = wave >> 1, hf = wave & 1;
    const int ml = lane & 15, q = lane >> 4;
    const int n0 = blockIdx.x * 64 + g * 32 + ml;
    const int n1 = n0 + 16;
    const int rr0 = (n0 < nrows) ? n0 : (nrows - 1);
    const int rr1 = (n1 < nrows) ? n1 : (nrows - 1);
    const bool ok0 = (n0 < nrows), ok1 = (n1 < nrows);

    bf16x8 bf0[4], bf1[4];
    {
        const float* x0 = X + (size_t)rr0 * D + q * 8;
        const float* x1 = X + (size_t)rr1 * D + q * 8;
#pragma unroll
        for (int kb = 0; kb < 4; ++kb) {
            float4 a0 = *(const float4*)(x0 + kb * 32);
            float4 a1 = *(const float4*)(x0 + kb * 32 + 4);
            float4 c0 = *(const float4*)(x1 + kb * 32);
            float4 c1 = *(const float4*)(x1 + kb * 32 + 4);
            bf16x8 v0, v1;
            v0[0] = (short)f2bf(a0.x); v0[1] = (short)f2bf(a0.y);
            v0[2] = (short)f2bf(a0.z); v0[3] = (short)f2bf(a0.w);
            v0[4] = (short)f2bf(a1.x); v0[5] = (short)f2bf(a1.y);
            v0[6] = (short)f2bf(a1.z); v0[7] = (short)f2bf(a1.w);
            v1[0] = (short)f2bf(c0.x); v1[1] = (short)f2bf(c0.y);
            v1[2] = (short)f2bf(c0.z); v1[3] = (short)f2bf(c0.w);
            v1[4] = (short)f2bf(c1.x); v1[5] = (short)f2bf(c1.y);
            v1[6] = (short)f2bf(c1.z); v1[7] = (short)f2bf(c1.w);
            bf0[kb] = v0; bf1[kb] = v1;
        }
    }

#pragma unroll
    for (int tl2 = 0; tl2 < 4; ++tl2) {
        const int tl = hf * 4 + tl2;
        floatx4 ac0 = {0.f, 0.f, 0.f, 0.f};
        floatx4 ac1 = {0.f, 0.f, 0.f, 0.f};
        const unsigned short* wp = Wt + (size_t)(tl * 16 + ml) * D + q * 8;
#pragma unroll
        for (int kb = 0; kb < 4; ++kb) {
            bf16x8 af = *(const bf16x8*)(wp + kb * 32);
            ac0 = __builtin_amdgcn_mfma_f32_16x16x32_bf16(af, bf0[kb], ac0, 0, 0, 0);
            ac1 = __builtin_amdgcn_mfma_f32_16x16x32_bf16(af, bf1[kb], ac1, 0, 0, 0);
        }
        const int f0i = tl * 16 + q * 4;
        float4 b4 = *(const float4*)(bias + f0i);
        if (ok0) {
            ushort4 o;
            o.x = f2bf(ac0[0] + b4.x); o.y = f2bf(ac0[1] + b4.y);
            o.z = f2bf(ac0[2] + b4.z); o.w = f2bf(ac0[3] + b4.w);
            *(ushort4*)(Y + (size_t)n0 * D + f0i) = o;
        }
        if (ok1) {
            ushort4 o;
            o.x = f2bf(ac1[0] + b4.x); o.y = f2bf(ac1[1] + b4.y);
            o.z = f2bf(ac1[2] + b4.z); o.w = f2bf(ac1[3] + b4.w);
            *(ushort4*)(Y + (size_t)n1 * D + f0i) = o;
        }
    }
}

// ---------------- gather segment-sum: agg[n] = sum hpre[edge_src[j]] (bf16, fp32 acc) -----
__global__ __launch_bounds__(256) void gather_sum(const unsigned short* __restrict__ hpre,
                                                  const int* __restrict__ offsets,
                                                  const int* __restrict__ edge_src,
                                                  unsigned short* __restrict__ agg, int nN) {
    const int t = threadIdx.x;
    const int li = t & 15;
    const int n = blockIdx.x * 16 + (t >> 4);
    if (n >= nN) return;
    const int beg = offsets[n], end = offsets[n + 1];

    float a[8] = {0.f, 0.f, 0.f, 0.f, 0.f, 0.f, 0.f, 0.f};
    int j = beg;
    int s0 = 0, s1 = 0;
    if (j < end) s0 = edge_src[j];
    if (j + 1 < end) s1 = edge_src[j + 1];

    while (j + 1 < end) {
        const int c0 = s0, c1 = s1;
        const int jn = j + 2;
        if (jn < end) s0 = edge_src[jn];
        if (jn + 1 < end) s1 = edge_src[jn + 1];
        bf16x8 v0 = *(const bf16x8*)(hpre + (size_t)c0 * D + li * 8);
        bf16x8 v1 = *(const bf16x8*)(hpre + (size_t)c1 * D + li * 8);
#pragma unroll
        for (int i = 0; i < 8; ++i)
            a[i] += bf2f((unsigned short)v0[i]) + bf2f((unsigned short)v1[i]);
        j = jn;
    }
    if (j < end) {
        bf16x8 v0 = *(const bf16x8*)(hpre + (size_t)s0 * D + li * 8);
#pragma unroll
        for (int i = 0; i < 8; ++i) a[i] += bf2f((unsigned short)v0[i]);
    }

    bf16x8 p;
#pragma unroll
    for (int i = 0; i < 8; ++i) p[i] = (short)f2bf(a[i]);
    *(bf16x8*)(agg + (size_t)n * D + li * 8) = p;
}

// ---------------- fused MLP: GEMM2(relu) -> GEMM3 -> +res -> LayerNorm ----------------
// Block = 4 waves = 64 nodes. Wave(g,hf): nodes g*32+ml, g*32+16+ml; tile half hf.
// 2 B-frags per wave share each weight A-load; t1 via LDS; LN halves combined via LDS.
__global__ __launch_bounds__(256) void fused_mlp(const unsigned short* __restrict__ agg,
                                                 const unsigned short* __restrict__ hpre,
                                                 const unsigned short* __restrict__ Wt1,
                                                 const float* __restrict__ b1,
                                                 const unsigned short* __restrict__ Wt2,
                                                 const float* __restrict__ b2,
                                                 const float* __restrict__ gamma,
                                                 const float* __restrict__ beta,
                                                 float* __restrict__ out, int nN) {
    __shared__ unsigned short tile[64 * TSTRIDE];   // 17.4 KB
    __shared__ float psm[2][64], psq[2][64];
    const int t = threadIdx.x;
    const int lane = t & 63, wave = t >> 6;
    const int g = wave >> 1, hf = wave & 1;
    const int ml = lane & 15, q = lane >> 4;
    const int lr0 = g * 32 + ml, lr1 = lr0 + 16;
    const int n0 = blockIdx.x * 64 + lr0;
    const int n1 = blockIdx.x * 64 + lr1;
    const int rr0 = (n0 < nN) ? n0 : (nN - 1);
    const int rr1 = (n1 < nN) ? n1 : (nN - 1);
    const bool ok0 = (n0 < nN), ok1 = (n1 < nN);

    // ---- GEMM2 (half): t1 features hf*64..hf*64+63 for both nodes -> LDS tile ----
    {
        bf16x8 bf0[4], bf1[4];
        const unsigned short* x0 = agg + (size_t)rr0 * D + q * 8;
        const unsigned short* x1 = agg + (size_t)rr1 * D + q * 8;
#pragma unroll
        for (int kb = 0; kb < 4; ++kb) {
            bf0[kb] = *(const bf16x8*)(x0 + kb * 32);
            bf1[kb] = *(const bf16x8*)(x1 + kb * 32);
        }

#pragma unroll
        for (int tl2 = 0; tl2 < 4; ++tl2) {
            const int tl = hf * 4 + tl2;
            floatx4 ac0 = {0.f, 0.f, 0.f, 0.f};
            floatx4 ac1 = {0.f, 0.f, 0.f, 0.f};
            const unsigned short* wp = Wt1 + (size_t)(tl * 16 + ml) * D + q * 8;
#pragma unroll
            for (int kb = 0; kb < 4; ++kb) {
                bf16x8 af = *(const bf16x8*)(wp + kb * 32);
                ac0 = __builtin_amdgcn_mfma_f32_16x16x32_bf16(af, bf0[kb], ac0, 0, 0, 0);
                ac1 = __builtin_amdgcn_mfma_f32_16x16x32_bf16(af, bf1[kb], ac1, 0, 0, 0);
            }
            const int f0i = tl * 16 + q * 4;
            float4 b4 = *(const float4*)(b1 + f0i);
            ushort4 o0, o1;
            o0.x = f2bf(fmaxf(ac0[0] + b4.x, 0.f));
            o0.y = f2bf(fmaxf(ac0[1] + b4.y, 0.f));
            o0.z = f2bf(fmaxf(ac0[2] + b4.z, 0.f));
            o0.w = f2bf(fmaxf(ac0[3] + b4.w, 0.f));
            o1.x = f2bf(fmaxf(ac1[0] + b4.x, 0.f));
            o1.y = f2bf(fmaxf(ac1[1] + b4.y, 0.f));
            o1.z = f2bf(fmaxf(ac1[2] + b4.z, 0.f));
            o1.w = f2bf(fmaxf(ac1[3] + b4.w, 0.f));
            *(ushort4*)(&tile[lr0 * TSTRIDE + f0i]) = o0;
            *(ushort4*)(&tile[lr1 * TSTRIDE + f0i]) = o1;
        }
    }
    __syncthreads();

    // ---- GEMM3 (half) + residual; partial LN sums ----
    float vs0[4][4], vs1[4][4];
    {
        bf16x8 bf0[4], bf1[4];
#pragma unroll
        for (int kb = 0; kb < 4; ++kb) {
            bf0[kb] = *(const bf16x8*)(&tile[lr0 * TSTRIDE + kb * 32 + q * 8]);
            bf1[kb] = *(const bf16x8*)(&tile[lr1 * TSTRIDE + kb * 32 + q * 8]);
        }

        float sm0 = 0.f, sq0 = 0.f, sm1 = 0.f, sq1 = 0.f;
#pragma unroll
        for (int tl2 = 0; tl2 < 4; ++tl2) {
            const int tl = hf * 4 + tl2;
            floatx4 ac0 = {0.f, 0.f, 0.f, 0.f};
            floatx4 ac1 = {0.f, 0.f, 0.f, 0.f};
            const unsigned short* wp = Wt2 + (size_t)(tl * 16 + ml) * D + q * 8;
#pragma unroll
            for (int kb = 0; kb < 4; ++kb) {
                bf16x8 af = *(const bf16x8*)(wp + kb * 32);
                ac0 = __builtin_amdgcn_mfma_f32_16x16x32_bf16(af, bf0[kb], ac0, 0, 0, 0);
                ac1 = __builtin_amdgcn_mfma_f32_16x16x32_bf16(af, bf1[kb], ac1, 0, 0, 0);
            }
            const int f0i = tl * 16 + q * 4;
            float4 b4 = *(const float4*)(b2 + f0i);
            ushort4 h0 = ((const ushort4*)(hpre + (size_t)rr0 * D + f0i))[0];
            ushort4 h1 = ((const ushort4*)(hpre + (size_t)rr1 * D + f0i))[0];
            float a0 = fmaxf(ac0[0] + b4.x, 0.f) + bf2f(h0.x);
            float a1 = fmaxf(ac0[1] + b4.y, 0.f) + bf2f(h0.y);
            float a2 = fmaxf(ac0[2] + b4.z, 0.f) + bf2f(h0.z);
            float a3 = fmaxf(ac0[3] + b4.w, 0.f) + bf2f(h0.w);
            float c0 = fmaxf(ac1[0] + b4.x, 0.f) + bf2f(h1.x);
            float c1 = fmaxf(ac1[1] + b4.y, 0.f) + bf2f(h1.y);
            float c2 = fmaxf(ac1[2] + b4.z, 0.f) + bf2f(h1.z);
            float c3 = fmaxf(ac1[3] + b4.w, 0.f) + bf2f(h1.w);
            vs0[tl2][0] = a0; vs0[tl2][1] = a1; vs0[tl2][2] = a2; vs0[tl2][3] = a3;
            vs1[tl2][0] = c0; vs1[tl2][1] = c1; vs1[tl2][2] = c2; vs1[tl2][3] = c3;
            sm0 += a0 + a1 + a2 + a3;
            sq0 += a0 * a0 + a1 * a1 + a2 * a2 + a3 * a3;
            sm1 += c0 + c1 + c2 + c3;
            sq1 += c0 * c0 + c1 * c1 + c2 * c2 + c3 * c3;
        }
        sm0 += __shfl_xor(sm0, 16); sm0 += __shfl_xor(sm0, 32);
        sq0 += __shfl_xor(sq0, 16); sq0 += __shfl_xor(sq0, 32);
        sm1 += __shfl_xor(sm1, 16); sm1 += __shfl_xor(sm1, 32);
        sq1 += __shfl_xor(sq1, 16); sq1 += __shfl_xor(sq1, 32);
        if (lane < 16) {
            psm[hf][lr0] = sm0; psq[hf][lr0] = sq0;
            psm[hf][lr1] = sm1; psq[hf][lr1] = sq1;
        }
    }
    __syncthreads();

    // ---- combine halves, normalize, write ----
    {
        const float smT0 = psm[0][lr0] + psm[1][lr0];
        const float sqT0 = psq[0][lr0] + psq[1][lr0];
        const float smT1 = psm[0][lr1] + psm[1][lr1];
        const float sqT1 = psq[0][lr1] + psq[1][lr1];
        const float mu0 = smT0 * (1.f / D);
        const float is0 = rsqrtf(sqT0 * (1.f / D) - mu0 * mu0 + EPS);
        const float mu1 = smT1 * (1.f / D);
        const float is1 = rsqrtf(sqT1 * (1.f / D) - mu1 * mu1 + EPS);

#pragma unroll
        for (int tl2 = 0; tl2 < 4; ++tl2) {
            const int f0i = (hf * 4 + tl2) * 16 + q * 4;
            float4 g4 = *(const float4*)(gamma + f0i);
            float4 be4 = *(const float4*)(beta + f0i);
            if (ok0) {
                float4 o;
                o.x = (vs0[tl2][0] - mu0) * is0 * g4.x + be4.x;
                o.y = (vs0[tl2][1] - mu0) * is0 * g4.y + be4.y;
                o.z = (vs0[tl2][2] - mu0) * is0 * g4.z + be4.z;
                o.w = (vs0[tl2][3] - mu0) * is0 * g4.w + be4.w;
                *(float4*)(out + (size_t)n0 * D + f0i) = o;
            }
            if (ok1) {
                float4 o;
                o.x = (vs1[tl2][0] - mu1) * is1 * g4.x + be4.x;
                o.y = (vs1[tl2][1] - mu1) * is1 * g4.y + be4.y;
                o.z = (vs1[tl2][2] - mu1) * is1 * g4.z + be4.z;
                o.w = (vs1[tl2][3] - mu1) * is1 * g4.w + be4.w;
                *(float4*)(out + (size_t)n1 * D + f0i) = o;
            }
        }
    }
}

extern "C" void kernel_launch(void* const* d_in, const int* in_sizes, int n_in,
                              void* d_out, int out_size, void* d_ws, size_t ws_size,
                              hipStream_t stream) {
    const float* h     = (const float*)d_in[0];
    const int*   src   = (const int*)d_in[1];
    const int*   dst   = (const int*)d_in[2];
    const float* W_pre = (const float*)d_in[3];
    const float* b_pre = (const float*)d_in[4];
    const float* W1    = (const float*)d_in[5];
    const float* b1    = (const float*)d_in[6];
    const float* W2    = (const float*)d_in[7];
    const float* b2    = (const float*)d_in[8];
    const float* gamma = (const float*)d_in[9];
    const float* beta  = (const float*)d_in[10];
    float* out = (float*)d_out;

    const int nN = in_sizes[0] / D;   // 50000
    const int nE = in_sizes[1];       // 600000
    const size_t rowsz = (size_t)nN * D;

    // ---- workspace layout ----
    unsigned short* hpre = (unsigned short*)d_ws;      // [nN*D] bf16
    unsigned short* agg  = hpre + rowsz;               // [nN*D] bf16
    unsigned short* wt   = agg + rowsz;                // [3*D*D] bf16
    int* edge_src  = (int*)(wt + 3 * D * D);           // [nE]
    int* offsets   = edge_src + nE;                    // [nN+1]
    int* cursor    = offsets + nN + 1;                 // [nN]
    int* counts    = cursor + nN;                      // [nN]
    int* chunkSums = counts + nN;                      // [64]

    const int prep_n  = (3 * D * D > nN) ? 3 * D * D : nN;
    const int eblocks = (nE + 255) / 256;
    const int gblocks = (nN + 63) / 64;    // 64 nodes per block
    const int nChunks = (nN + SCAN_CHUNK - 1) / SCAN_CHUNK;   // 49

    prep<<<(prep_n + 255) / 256, 256, 0, stream>>>(W_pre, W1, W2, wt, counts, offsets, nN, nE);
    hist_dst<<<eblocks, 256, 0, stream>>>(dst, counts, nE);
    scan_chunk_sums<<<nChunks, 256, 0, stream>>>(counts, chunkSums, nN);
    scan_final<<<nChunks, 256, 0, stream>>>(counts, chunkSums, nChunks, offsets, cursor, nN);
    fill_edges<<<eblocks, 256, 0, stream>>>(src, dst, cursor, edge_src, nE);

    gemm1<<<gblocks, 256, 0, stream>>>(h, wt, b_pre, hpre, nN);
    gather_sum<<<(nN + 15) / 16, 256, 0, stream>>>(hpre, offsets, edge_src, agg, nN);
    fused_mlp<<<gblocks, 256, 0, stream>>>(agg, hpre, wt + D * D, b1, wt + 2 * D * D, b2,
                                           gamma, beta, out, nN);
}